// Round 9
// baseline (2575.444 us; speedup 1.0000x reference)
//
#include <hip/hip_runtime.h>

static constexpr int SEQ   = 256;
static constexpr int BATCH = 32;
static constexpr int EMB   = 25;
static constexpr int HID   = 4096;
static constexpr int NBLK  = 256;           // one block per CU (co-resident)
static constexpr int NTHR  = 256;           // 4 waves, 1 per SIMD
static constexpr int RPB   = HID / NBLK;    // 16 rows of h per block
static constexpr int CPT   = HID / NTHR;    // 16 cols per thread

typedef unsigned u32x4 __attribute__((ext_vector_type(4)));

// Persistent kernel, dataflow-synced: h is stored as (value,stamp) 8B pairs via
// single dwordx2 sc0 sc1 stores (L1/L2 bypass, L3 = coherence point). Consumers
// poll-load their own 16 pairs and proceed when stamps match — data+validity in
// ONE L3 round trip. No flags, no grid barrier, no fences, no memset (stamp
// check is poison-proof: want in 1..255, poison = 0xAAAAAAAA). 2-buffer safety:
// writing h_{t+1} requires having observed ALL stamps of h_t, which requires
// every block's mid-iteration __syncthreads, which orders all h_{t-1} reads
// before that block's h_t store => max skew < 1 iteration.
__global__ __launch_bounds__(NTHR, 1)
void rnn_persistent(const float* __restrict__ x,
                    const float* __restrict__ W_ih,
                    const float* __restrict__ W_hh,
                    const float* __restrict__ b_ih,
                    const float* __restrict__ b_hh,
                    float* __restrict__ out,
                    unsigned long long* __restrict__ hbuf2) // 2*HID pairs
{
    const int blk  = blockIdx.x;
    const int tid  = threadIdx.x;
    const int R0   = blk * RPB;
    const int C0   = tid * CPT;
    const int wave = tid >> 6;
    const int lane = tid & 63;

    __shared__ float ldsW[RPB * EMB];      // W_ih rows for this block
    __shared__ float ldsP[SEQ][RPB];       // precomputed input projection
    __shared__ float ldsRed[2][4][RPB];    // cross-wave partials, dbuf by t&1

    // ---- W_ih slice -> LDS ----
    for (int i = tid; i < RPB * EMB; i += NTHR)
        ldsW[i] = W_ih[(size_t)R0 * EMB + i];
    __syncthreads();

    // ---- precompute p[t][row] = x[t][31]·W_ih[row] + b_ih + b_hh ----
    for (int idx = tid; idx < SEQ * RPB; idx += NTHR) {
        const int s = idx >> 4;
        const int r = idx & 15;
        const float* xt = x + ((size_t)s * BATCH + (BATCH - 1)) * EMB;
        float p = b_ih[R0 + r] + b_hh[R0 + r];
#pragma unroll
        for (int e = 0; e < EMB; ++e)
            p = fmaf(xt[e], ldsW[r * EMB + e], p);
        ldsP[s][r] = p;
    }

    // ---- register-resident W_hh tile (static indexing only -> regs) ----
    float w[RPB][CPT];
#pragma unroll
    for (int r = 0; r < RPB; ++r) {
        const float4* src = reinterpret_cast<const float4*>(
            W_hh + (size_t)(R0 + r) * HID + C0);
#pragma unroll
        for (int q = 0; q < 4; ++q) {
            const float4 v = src[q];
            w[r][4*q+0] = v.x; w[r][4*q+1] = v.y;
            w[r][4*q+2] = v.z; w[r][4*q+3] = v.w;
        }
    }
    __syncthreads();   // ldsP complete before use

    for (int t = 0; t < SEQ; ++t) {
        // ---- acquire h_{t-1}: poll own 16 (value,stamp) pairs ----
        float hv[CPT];
        if (t == 0) {
#pragma unroll
            for (int c = 0; c < CPT; ++c) hv[c] = 0.0f;
        } else {
            const unsigned long long* hp = hbuf2 + ((t - 1) & 1) * HID + C0;
            const unsigned want = (unsigned)t;   // stamp(h_{t-1}) = (t-1)+1
            u32x4 p0, p1, p2, p3, p4, p5, p6, p7;
            for (int it = 0; it < (1 << 15); ++it) {
                asm volatile(
                    "global_load_dwordx4 %0, %8, off sc0 sc1\n\t"
                    "global_load_dwordx4 %1, %8, off offset:16 sc0 sc1\n\t"
                    "global_load_dwordx4 %2, %8, off offset:32 sc0 sc1\n\t"
                    "global_load_dwordx4 %3, %8, off offset:48 sc0 sc1\n\t"
                    "global_load_dwordx4 %4, %8, off offset:64 sc0 sc1\n\t"
                    "global_load_dwordx4 %5, %8, off offset:80 sc0 sc1\n\t"
                    "global_load_dwordx4 %6, %8, off offset:96 sc0 sc1\n\t"
                    "global_load_dwordx4 %7, %8, off offset:112 sc0 sc1\n\t"
                    "s_waitcnt vmcnt(0)"
                    : "=&v"(p0), "=&v"(p1), "=&v"(p2), "=&v"(p3),
                      "=&v"(p4), "=&v"(p5), "=&v"(p6), "=&v"(p7)
                    : "v"(hp) : "memory");
                const bool ok =
                    (p0[1] == want) & (p0[3] == want) &
                    (p1[1] == want) & (p1[3] == want) &
                    (p2[1] == want) & (p2[3] == want) &
                    (p3[1] == want) & (p3[3] == want) &
                    (p4[1] == want) & (p4[3] == want) &
                    (p5[1] == want) & (p5[3] == want) &
                    (p6[1] == want) & (p6[3] == want) &
                    (p7[1] == want) & (p7[3] == want);
                if (ok) break;   // lanes that pass wait masked for the wave
            }
            hv[ 0] = __uint_as_float(p0[0]); hv[ 1] = __uint_as_float(p0[2]);
            hv[ 2] = __uint_as_float(p1[0]); hv[ 3] = __uint_as_float(p1[2]);
            hv[ 4] = __uint_as_float(p2[0]); hv[ 5] = __uint_as_float(p2[2]);
            hv[ 6] = __uint_as_float(p3[0]); hv[ 7] = __uint_as_float(p3[2]);
            hv[ 8] = __uint_as_float(p4[0]); hv[ 9] = __uint_as_float(p4[2]);
            hv[10] = __uint_as_float(p5[0]); hv[11] = __uint_as_float(p5[2]);
            hv[12] = __uint_as_float(p6[0]); hv[13] = __uint_as_float(p6[2]);
            hv[14] = __uint_as_float(p7[0]); hv[15] = __uint_as_float(p7[2]);
        }

        // ---- partial dots, fp64 accumulate (w fp32 in regs) ----
        double acc[RPB];
#pragma unroll
        for (int r = 0; r < RPB; ++r) acc[r] = 0.0;
#pragma unroll
        for (int c = 0; c < CPT; ++c) {
            const double hd = (double)hv[c];
#pragma unroll
            for (int r = 0; r < RPB; ++r)
                acc[r] = fma((double)w[r][c], hd, acc[r]);
        }

        // ---- reduce: fp32 butterfly across wave, LDS across waves ----
        float accf[RPB];
#pragma unroll
        for (int r = 0; r < RPB; ++r) accf[r] = (float)acc[r];
#pragma unroll
        for (int off = 32; off >= 1; off >>= 1)
#pragma unroll
            for (int r = 0; r < RPB; ++r)
                accf[r] += __shfl_xor(accf[r], off, 64);
        if (lane == 0) {
#pragma unroll
            for (int r = 0; r < RPB; ++r)
                ldsRed[t & 1][wave][r] = accf[r];
        }
        __syncthreads();   // flow-dep: partials visible to wave 0

        // ---- epilogue: wave 0 finishes 16 rows, stores (h, stamp) ----
        if (wave == 0 && lane < RPB) {
            const float s4 = ldsRed[t & 1][0][lane] + ldsRed[t & 1][1][lane]
                           + ldsRed[t & 1][2][lane] + ldsRed[t & 1][3][lane];
            const float h = tanhf(s4 + ldsP[t][lane]);
            const unsigned long long packed =
                ((unsigned long long)(unsigned)(t + 1) << 32) |
                (unsigned long long)__float_as_uint(h);
            unsigned long long* hd = hbuf2 + (t & 1) * HID + R0 + lane;
            asm volatile("global_store_dwordx2 %0, %1, off sc0 sc1"
                         :: "v"(hd), "v"(packed) : "memory");
            out[(size_t)t * HID + R0 + lane] = h;   // cached, off crit path
        }
        // no trailing barrier: anti-deps covered by the dataflow proof above
    }
}

extern "C" void kernel_launch(void* const* d_in, const int* in_sizes, int n_in,
                              void* d_out, int out_size, void* d_ws, size_t ws_size,
                              hipStream_t stream) {
    const float* x    = (const float*)d_in[0];
    const float* W_ih = (const float*)d_in[1];
    const float* W_hh = (const float*)d_in[2];
    const float* b_ih = (const float*)d_in[3];
    const float* b_hh = (const float*)d_in[4];
    float* out = (float*)d_out;

    // 2 buffers x HID (value,stamp) pairs = 64 KB. No init needed: stamp
    // check never passes on 0xAA poison, and every pair is written before read.
    unsigned long long* hbuf2 = (unsigned long long*)d_ws;

    rnn_persistent<<<dim3(NBLK), dim3(NTHR), 0, stream>>>(
        x, W_ih, W_hh, b_ih, b_hh, out, hbuf2);
}